// Round 2
// baseline (202.975 us; speedup 1.0000x reference)
//
#include <hip/hip_runtime.h>
#include <hip/hip_bf16.h>
#include <math.h>

// Problem constants (from reference setup)
#define DHID 320     // hidden dim D
#define KNN  30      // neighbors per node

typedef float f4 __attribute__((ext_vector_type(4)));

// ---------------------------------------------------------------------------
// Kernel A: per-node attention + aggregation + coord update (one wave/node).
// Online softmax over the K=30 contiguous edges of each node.
// Lane l owns dims {4l..4l+3} (float4) and {256+l} (tail) of the 320-dim row.
// ---------------------------------------------------------------------------
__global__ __launch_bounds__(256)
void edge_kernel(const float* __restrict__ h,
                 const float* __restrict__ coord,
                 const int*   __restrict__ col,       // edge_index row 1
                 float*       __restrict__ agg,       // [N, D] out (softmax-weighted sum)
                 float*       __restrict__ coord_out, // [N, 3] out
                 int N)
{
    int wid  = (int)((blockIdx.x * 256u + threadIdx.x) >> 6);
    int lane = threadIdx.x & 63;
    if (wid >= N) return;

    const float* hi = h + (size_t)wid * DHID;
    f4    hv = *(const f4*)(hi + 4 * lane);
    float ht = hi[256 + lane];

    float cx = coord[3 * wid + 0];
    float cy = coord[3 * wid + 1];
    float cz = coord[3 * wid + 2];

    // load the 30 neighbor indices once (lanes 0..29), broadcast via shfl
    const int* cp = col + (size_t)wid * KNN;
    int jv = (lane < KNN) ? cp[lane] : 0;

    float run_m = -INFINITY, run_l = 0.f;
    f4    accv = {0.f, 0.f, 0.f, 0.f};
    float acct = 0.f;
    float ax = 0.f, ay = 0.f, az = 0.f;

#pragma unroll 2
    for (int k = 0; k < KNN; ++k) {
        int j = __shfl(jv, k);
        const float* hj = h + (size_t)j * DHID;
        f4    gv = *(const f4*)(hj + 4 * lane);
        float gt = hj[256 + lane];

        float dot = hv[0] * gv[0];
        dot = fmaf(hv[1], gv[1], dot);
        dot = fmaf(hv[2], gv[2], dot);
        dot = fmaf(hv[3], gv[3], dot);
        dot = fmaf(ht, gt, dot);
        // butterfly: all 64 lanes end with the full 320-dot
#pragma unroll
        for (int off = 32; off; off >>= 1) dot += __shfl_xor(dot, off);

        float dx = cx - coord[3 * j + 0];
        float dy = cy - coord[3 * j + 1];
        float dz = cz - coord[3 * j + 2];
        float radial = dx * dx + dy * dy + dz * dz;
        float s = dot + 1.0f / (radial + 1e-8f);   // DIST_W = 1.0, EPS = 1e-8

        float nm = fmaxf(run_m, s);
        float sc = __expf(run_m - nm);             // first iter: exp(-inf)=0
        float w  = __expf(s - nm);
        run_l = run_l * sc + w;
        accv  = accv * sc + w * gv;
        acct  = acct * sc + w * gt;
        ax = ax * sc + w * dx;
        ay = ay * sc + w * dy;
        az = az * sc + w * dz;
        run_m = nm;
    }

    float inv = 1.0f / run_l;
    float* ao = agg + (size_t)wid * DHID;
    *(f4*)(ao + 4 * lane) = accv * inv;
    ao[256 + lane] = acct * inv;

    if (lane == 0) {
        float s = inv / (float)KNN;   // mean over K of softmax-weighted diffs
        coord_out[3 * wid + 0] = cx + ax * s;
        coord_out[3 * wid + 1] = cy + ay * s;
        coord_out[3 * wid + 2] = cz + az * s;
    }
}

// ---------------------------------------------------------------------------
// Kernel B: node MLP with residual.
// z = [h | agg] (N x 640); out = silu(z@W1 + b1)@W2 + b2; hout = h + out
// 256 threads (4 waves), 16 rows/block, 4 rows/wave.
// Lane owns output cols {4l..4l+3} (float4) + {256+l} (tail).
// LDS: one 16x640 buffer; the agg half is reused for the hidden activations
// after layer 1 (h half stays intact for the residual).
// ---------------------------------------------------------------------------
#define ROWS 16

__global__ __launch_bounds__(256)
void mlp_kernel(const float* __restrict__ h,
                const float* __restrict__ agg,
                const float* __restrict__ W1,   // [640, 320] row-major
                const float* __restrict__ b1,   // [320]
                const float* __restrict__ W2,   // [320, 320]
                const float* __restrict__ b2,   // [320]
                float*       __restrict__ hout)
{
    __shared__ float zs[ROWS][2 * DHID];   // 40 KiB

    const int tid  = threadIdx.x;
    const int lane = tid & 63;
    const int wv   = tid >> 6;
    const int r0   = blockIdx.x * ROWS;

    // stage z = [h | agg] for 16 rows, float4-coalesced (5 iters/half)
    {
        const f4* hp = (const f4*)(h   + (size_t)r0 * DHID);
        const f4* ap = (const f4*)(agg + (size_t)r0 * DHID);
        for (int idx = tid; idx < ROWS * (DHID / 4); idx += 256) {
            int r = idx / (DHID / 4), c = idx - r * (DHID / 4);
            *(f4*)&zs[r][4 * c]        = hp[idx];
            *(f4*)&zs[r][DHID + 4 * c] = ap[idx];
        }
    }
    __syncthreads();

    // ---- layer 1: [16 x 640] @ [640 x 320] ----
    f4    a1v[4] = {};
    float a1t[4] = {0.f, 0.f, 0.f, 0.f};

    for (int k = 0; k < 2 * DHID; k += 4) {
        f4 zq[4];
#pragma unroll
        for (int r = 0; r < 4; ++r) zq[r] = *(const f4*)&zs[wv * 4 + r][k];
#pragma unroll
        for (int kk = 0; kk < 4; ++kk) {
            const float* wr = W1 + (size_t)(k + kk) * DHID;
            f4    w4 = *(const f4*)(wr + 4 * lane);
            float wt = wr[256 + lane];
#pragma unroll
            for (int r = 0; r < 4; ++r) {
                float z = zq[r][kk];
                a1v[r] += z * w4;
                a1t[r] = fmaf(z, wt, a1t[r]);
            }
        }
    }

    __syncthreads();   // everyone done reading the agg half of zs

    {
        f4    bb = *(const f4*)(b1 + 4 * lane);
        float bt = b1[256 + lane];
#pragma unroll
        for (int r = 0; r < 4; ++r) {
            f4 x = a1v[r] + bb;
            f4 sv;
#pragma unroll
            for (int i = 0; i < 4; ++i) sv[i] = x[i] / (1.f + __expf(-x[i]));
            *(f4*)&zs[wv * 4 + r][DHID + 4 * lane] = sv;     // hidden into agg half
            float xt = a1t[r] + bt;
            zs[wv * 4 + r][DHID + 256 + lane] = xt / (1.f + __expf(-xt));
        }
    }
    __syncthreads();

    // ---- layer 2: [16 x 320] @ [320 x 320] ----
    f4    a2v[4] = {};
    float a2t[4] = {0.f, 0.f, 0.f, 0.f};

    for (int k = 0; k < DHID; k += 4) {
        f4 zq[4];
#pragma unroll
        for (int r = 0; r < 4; ++r) zq[r] = *(const f4*)&zs[wv * 4 + r][DHID + k];
#pragma unroll
        for (int kk = 0; kk < 4; ++kk) {
            const float* wr = W2 + (size_t)(k + kk) * DHID;
            f4    w4 = *(const f4*)(wr + 4 * lane);
            float wt = wr[256 + lane];
#pragma unroll
            for (int r = 0; r < 4; ++r) {
                float z = zq[r][kk];
                a2v[r] += z * w4;
                a2t[r] = fmaf(z, wt, a2t[r]);
            }
        }
    }

    {
        f4    bb = *(const f4*)(b2 + 4 * lane);
        float bt = b2[256 + lane];
#pragma unroll
        for (int r = 0; r < 4; ++r) {
            int row = r0 + wv * 4 + r;
            f4 res = *(const f4*)&zs[wv * 4 + r][4 * lane];   // h half = residual
            *(f4*)(hout + (size_t)row * DHID + 4 * lane) = a2v[r] + bb + res;
            hout[(size_t)row * DHID + 256 + lane] =
                a2t[r] + bt + zs[wv * 4 + r][256 + lane];
        }
    }
}

// ---------------------------------------------------------------------------
extern "C" void kernel_launch(void* const* d_in, const int* in_sizes, int n_in,
                              void* d_out, int out_size, void* d_ws, size_t ws_size,
                              hipStream_t stream)
{
    const float* h     = (const float*)d_in[0];
    const float* coord = (const float*)d_in[1];
    const float* W1    = (const float*)d_in[2];
    const float* b1    = (const float*)d_in[3];
    const float* W2    = (const float*)d_in[4];
    const float* b2    = (const float*)d_in[5];
    const int*   ei    = (const int*)d_in[6];   // [2, N*K] int32

    const int N  = in_sizes[0] / DHID;          // 8192
    const int NK = N * KNN;

    float* out       = (float*)d_out;
    float* hout      = out;                     // [N, 320]
    float* coord_out = out + (size_t)N * DHID;  // [N, 3]

    // agg scratch: prefer d_ws; fall back to writing into the hout region
    // (safe: each MLP block stages its own agg rows into LDS before writing).
    float* agg = ((size_t)N * DHID * sizeof(float) <= ws_size)
                   ? (float*)d_ws : hout;

    const int* col = ei + NK;                   // second row of edge_index

    edge_kernel<<<N / 4, 256, 0, stream>>>(h, coord, col, agg, coord_out, N);
    mlp_kernel<<<N / ROWS, 256, 0, stream>>>(h, agg, W1, b1, W2, b2, hout);
}

// Round 3
// 167.212 us; speedup vs baseline: 1.2139x; 1.2139x over previous
//
#include <hip/hip_runtime.h>
#include <hip/hip_bf16.h>
#include <math.h>

// Problem constants (from reference setup)
#define DHID 320     // hidden dim D
#define KNN  30      // neighbors per node

typedef float f4    __attribute__((ext_vector_type(4)));
typedef float f32x4 __attribute__((ext_vector_type(4)));
typedef short bf16x8 __attribute__((ext_vector_type(8)));
typedef short bf16x4 __attribute__((ext_vector_type(4)));

// fp32 -> bf16 bits, round-to-nearest-even
static __device__ __forceinline__ short f2bf(float x) {
    union { float f; unsigned u; } v; v.f = x;
    unsigned r = v.u + 0x7FFFu + ((v.u >> 16) & 1u);
    return (short)(r >> 16);
}

// ---------------------------------------------------------------------------
// Kernel A: per-node attention + aggregation + coord update (one wave/node).
// Online softmax over the K=30 contiguous edges of each node.
// Lane l owns dims {4l..4l+3} (float4) and {256+l} (tail) of the 320-dim row.
// agg is emitted as bf16 (feeds the MFMA MLP directly).
// ---------------------------------------------------------------------------
__global__ __launch_bounds__(256)
void edge_kernel(const float* __restrict__ h,
                 const float* __restrict__ coord,
                 const int*   __restrict__ col,       // edge_index row 1
                 short*       __restrict__ aggb,      // [N, D] bf16 out
                 float*       __restrict__ coord_out, // [N, 3] out
                 int N)
{
    int wid  = (int)((blockIdx.x * 256u + threadIdx.x) >> 6);
    int lane = threadIdx.x & 63;
    if (wid >= N) return;

    const float* hi = h + (size_t)wid * DHID;
    f4    hv = *(const f4*)(hi + 4 * lane);
    float ht = hi[256 + lane];

    float cx = coord[3 * wid + 0];
    float cy = coord[3 * wid + 1];
    float cz = coord[3 * wid + 2];

    // load the 30 neighbor indices once (lanes 0..29), broadcast via shfl
    const int* cp = col + (size_t)wid * KNN;
    int jv = (lane < KNN) ? cp[lane] : 0;

    float run_m = -INFINITY, run_l = 0.f;
    f4    accv = {0.f, 0.f, 0.f, 0.f};
    float acct = 0.f;
    float ax = 0.f, ay = 0.f, az = 0.f;

#pragma unroll 2
    for (int k = 0; k < KNN; ++k) {
        int j = __shfl(jv, k);
        const float* hj = h + (size_t)j * DHID;
        f4    gv = *(const f4*)(hj + 4 * lane);
        float gt = hj[256 + lane];

        float dot = hv[0] * gv[0];
        dot = fmaf(hv[1], gv[1], dot);
        dot = fmaf(hv[2], gv[2], dot);
        dot = fmaf(hv[3], gv[3], dot);
        dot = fmaf(ht, gt, dot);
        // butterfly: all 64 lanes end with the full 320-dot
#pragma unroll
        for (int off = 32; off; off >>= 1) dot += __shfl_xor(dot, off);

        float dx = cx - coord[3 * j + 0];
        float dy = cy - coord[3 * j + 1];
        float dz = cz - coord[3 * j + 2];
        float radial = dx * dx + dy * dy + dz * dz;
        float s = dot + 1.0f / (radial + 1e-8f);   // DIST_W = 1.0, EPS = 1e-8

        float nm = fmaxf(run_m, s);
        float sc = __expf(run_m - nm);             // first iter: exp(-inf)=0
        float w  = __expf(s - nm);
        run_l = run_l * sc + w;
        accv  = accv * sc + w * gv;
        acct  = acct * sc + w * gt;
        ax = ax * sc + w * dx;
        ay = ay * sc + w * dy;
        az = az * sc + w * dz;
        run_m = nm;
    }

    float inv = 1.0f / run_l;
    short* ao = aggb + (size_t)wid * DHID;
    bf16x4 o;
#pragma unroll
    for (int i = 0; i < 4; ++i) o[i] = f2bf(accv[i] * inv);
    *(bf16x4*)(ao + 4 * lane) = o;                // 8B store
    ao[256 + lane] = f2bf(acct * inv);

    if (lane == 0) {
        float s = inv / (float)KNN;   // mean over K of softmax-weighted diffs
        coord_out[3 * wid + 0] = cx + ax * s;
        coord_out[3 * wid + 1] = cy + ay * s;
        coord_out[3 * wid + 2] = cz + az * s;
    }
}

// ---------------------------------------------------------------------------
// Kernel 0: convert + transpose weights to bf16.
// Wt1[c][k] = bf16(W1[k][c])   (320 x 640)
// Wt2[c][k] = bf16(W2[k][c])   (320 x 320)
// B-fragment for mfma_16x16x32 then = one 16B load of 8 contiguous k.
// ---------------------------------------------------------------------------
__global__ __launch_bounds__(256)
void wconv_kernel(const float* __restrict__ W1, const float* __restrict__ W2,
                  short* __restrict__ Wt1, short* __restrict__ Wt2)
{
    int i = blockIdx.x * 256 + threadIdx.x;
    if (i < 640 * 320) {
        int k = i / 320, c = i - k * 320;
        Wt1[c * 640 + k] = f2bf(W1[i]);
    } else {
        int j = i - 640 * 320;
        int k = j / 320, c = j - k * 320;
        Wt2[c * 320 + k] = f2bf(W2[j]);
    }
}

// ---------------------------------------------------------------------------
// Kernel B: node MLP via bf16 MFMA.
// z = [h | agg] (N x 640); out = silu(z@W1+b1)@W2 + b2; hout = h + out
// Block: 256 threads = 4 waves, 16 rows. Waves col-split: wave wv owns
// col-tiles wv*5 .. wv*5+4 (16 cols each). K-loop: 20 steps of 32 (GEMM1),
// 10 steps (GEMM2). A-frag: row = lane&15, k = t*32 + (lane>>4)*8 + j.
// Hidden activations go through a XOR-swizzled bf16 LDS tile.
// ---------------------------------------------------------------------------
__global__ __launch_bounds__(256)
void mlp_mfma_kernel(const float* __restrict__ h,
                     const short* __restrict__ aggb,
                     const short* __restrict__ Wt1,
                     const short* __restrict__ Wt2,
                     const float* __restrict__ b1,
                     const float* __restrict__ b2,
                     float*       __restrict__ hout)
{
    __shared__ short h1s[16 * DHID];    // [16][320] bf16, XOR-swizzled, 10 KiB

    const int tid  = threadIdx.x;
    const int lane = tid & 63;
    const int wv   = tid >> 6;
    const int lrow = lane & 15;         // M index within 16-row tile
    const int kg   = lane >> 4;         // k-group 0..3
    const int r0   = blockIdx.x * 16;
    const int c0   = wv * 5;            // first col-tile of this wave

    // ---- GEMM1: [16 x 640] @ W1 -> silu -> LDS ----
    f32x4 acc[5] = {};

    const float* hA = h    + (size_t)(r0 + lrow) * DHID + kg * 8;
    const short* gA = aggb + (size_t)(r0 + lrow) * DHID + kg * 8;
    const short* bB1 = Wt1 + kg * 8;    // + col*640 + t*32

    // k in [0,320): A from h (fp32 -> bf16)
    for (int t = 0; t < 10; ++t) {
        f4 lo = *(const f4*)(hA + t * 32);
        f4 hi = *(const f4*)(hA + t * 32 + 4);
        bf16x8 a;
#pragma unroll
        for (int j = 0; j < 4; ++j) { a[j] = f2bf(lo[j]); a[4 + j] = f2bf(hi[j]); }
#pragma unroll
        for (int c = 0; c < 5; ++c) {
            bf16x8 b = *(const bf16x8*)(bB1 + (size_t)((c0 + c) * 16 + lrow) * 640 + t * 32);
            acc[c] = __builtin_amdgcn_mfma_f32_16x16x32_bf16(a, b, acc[c], 0, 0, 0);
        }
    }
    // k in [320,640): A from aggb (already bf16)
    for (int t = 0; t < 10; ++t) {
        bf16x8 a = *(const bf16x8*)(gA + t * 32);
#pragma unroll
        for (int c = 0; c < 5; ++c) {
            bf16x8 b = *(const bf16x8*)(bB1 + (size_t)((c0 + c) * 16 + lrow) * 640 + (t + 10) * 32);
            acc[c] = __builtin_amdgcn_mfma_f32_16x16x32_bf16(a, b, acc[c], 0, 0, 0);
        }
    }

    // epilogue 1: bias + SiLU -> swizzled LDS (row=(kg*4+r), col=tile*16+lrow)
#pragma unroll
    for (int c = 0; c < 5; ++c) {
        int colc = (c0 + c) * 16 + lrow;
        float bb = b1[colc];
#pragma unroll
        for (int r = 0; r < 4; ++r) {
            int row = kg * 4 + r;
            float x = acc[c][r] + bb;
            x = x / (1.f + __expf(-x));
            h1s[row * DHID + (colc ^ ((row & 7) << 3))] = f2bf(x);
        }
    }
    __syncthreads();

    // ---- GEMM2: [16 x 320] @ W2 ----
    f32x4 acc2[5] = {};
    const short* bB2 = Wt2 + kg * 8;
    const char*  h1base = (const char*)h1s + lrow * (DHID * 2);
    const int    swz = (lrow & 7) << 4;

    for (int t = 0; t < 10; ++t) {
        bf16x8 a = *(const bf16x8*)(h1base + ((t * 64 + kg * 16) ^ swz));
#pragma unroll
        for (int c = 0; c < 5; ++c) {
            bf16x8 b = *(const bf16x8*)(bB2 + (size_t)((c0 + c) * 16 + lrow) * 320 + t * 32);
            acc2[c] = __builtin_amdgcn_mfma_f32_16x16x32_bf16(a, b, acc2[c], 0, 0, 0);
        }
    }

    // epilogue 2: bias + residual -> hout
#pragma unroll
    for (int c = 0; c < 5; ++c) {
        int colc = (c0 + c) * 16 + lrow;
        float bb = b2[colc];
#pragma unroll
        for (int r = 0; r < 4; ++r) {
            int grow = r0 + kg * 4 + r;
            hout[(size_t)grow * DHID + colc] =
                acc2[c][r] + bb + h[(size_t)grow * DHID + colc];
        }
    }
}

// ---------------------------------------------------------------------------
extern "C" void kernel_launch(void* const* d_in, const int* in_sizes, int n_in,
                              void* d_out, int out_size, void* d_ws, size_t ws_size,
                              hipStream_t stream)
{
    const float* h     = (const float*)d_in[0];
    const float* coord = (const float*)d_in[1];
    const float* W1    = (const float*)d_in[2];
    const float* b1    = (const float*)d_in[3];
    const float* W2    = (const float*)d_in[4];
    const float* b2    = (const float*)d_in[5];
    const int*   ei    = (const int*)d_in[6];   // [2, N*K] int32

    const int N  = in_sizes[0] / DHID;          // 8192
    const int NK = N * KNN;

    float* out       = (float*)d_out;
    float* hout      = out;                     // [N, 320]
    float* coord_out = out + (size_t)N * DHID;  // [N, 3]

    // workspace layout (bf16 buffers):
    //   aggb [N*320]   : 5,242,880 B
    //   Wt1  [320*640] :   409,600 B
    //   Wt2  [320*320] :   204,800 B
    short* aggb = (short*)d_ws;
    short* Wt1  = aggb + (size_t)N * DHID;
    short* Wt2  = Wt1 + 320 * 640;

    const int* col = ei + NK;                   // second row of edge_index

    wconv_kernel<<<(640 * 320 + 320 * 320) / 256, 256, 0, stream>>>(W1, W2, Wt1, Wt2);
    edge_kernel<<<N / 4, 256, 0, stream>>>(h, coord, col, aggb, coord_out, N);
    mlp_mfma_kernel<<<N / 16, 256, 0, stream>>>(h, aggb, Wt1, Wt2, b1, b2, hout);
}

// Round 10
// 139.083 us; speedup vs baseline: 1.4594x; 1.2022x over previous
//
#include <hip/hip_runtime.h>
#include <hip/hip_bf16.h>
#include <math.h>

// Problem constants (from reference setup)
#define DHID 320     // hidden dim D
#define KNN  30      // neighbors per node

typedef float f4    __attribute__((ext_vector_type(4)));
typedef float f32x4 __attribute__((ext_vector_type(4)));
typedef short bf16x8 __attribute__((ext_vector_type(8)));
typedef short bf16x4 __attribute__((ext_vector_type(4)));

// fp32 -> bf16 bits, round-to-nearest-even
static __device__ __forceinline__ short f2bf(float x) {
    union { float f; unsigned u; } v; v.f = x;
    unsigned r = v.u + 0x7FFFu + ((v.u >> 16) & 1u);
    return (short)(r >> 16);
}

// ---------------------------------------------------------------------------
// Kernel A: per-node attention + aggregation + coord update (one wave/node).
// Online softmax over the K=30 contiguous edges of each node.
// Lane l owns dims {4l..4l+3} (float4) and {256+l} (tail) of the 320-dim row.
// ---------------------------------------------------------------------------
__global__ __launch_bounds__(256)
void edge_kernel(const float* __restrict__ h,
                 const float* __restrict__ coord,
                 const int*   __restrict__ col,       // edge_index row 1
                 short*       __restrict__ aggb,      // [N, D] bf16 out
                 float*       __restrict__ coord_out, // [N, 3] out
                 int N)
{
    int wid  = (int)((blockIdx.x * 256u + threadIdx.x) >> 6);
    int lane = threadIdx.x & 63;
    if (wid >= N) return;

    const float* hi = h + (size_t)wid * DHID;
    f4    hv = *(const f4*)(hi + 4 * lane);
    float ht = hi[256 + lane];

    float cx = coord[3 * wid + 0];
    float cy = coord[3 * wid + 1];
    float cz = coord[3 * wid + 2];

    // load the 30 neighbor indices + their coords once (lanes 0..29)
    const int* cp = col + (size_t)wid * KNN;
    int jv = (lane < KNN) ? cp[lane] : 0;
    float pjx = 0.f, pjy = 0.f, pjz = 0.f;
    if (lane < KNN) {
        pjx = coord[3 * jv + 0];
        pjy = coord[3 * jv + 1];
        pjz = coord[3 * jv + 2];
    }

    float run_m = -INFINITY, run_l = 0.f;
    f4    accv = {0.f, 0.f, 0.f, 0.f};
    float acct = 0.f;
    float ax = 0.f, ay = 0.f, az = 0.f;

#pragma unroll 2
    for (int k = 0; k < KNN; ++k) {
        int j = __shfl(jv, k);
        const float* hj = h + (size_t)j * DHID;
        f4    gv = *(const f4*)(hj + 4 * lane);
        float gt = hj[256 + lane];

        float dot = hv[0] * gv[0];
        dot = fmaf(hv[1], gv[1], dot);
        dot = fmaf(hv[2], gv[2], dot);
        dot = fmaf(hv[3], gv[3], dot);
        dot = fmaf(ht, gt, dot);
        // butterfly: all 64 lanes end with the full 320-dot
#pragma unroll
        for (int off = 32; off; off >>= 1) dot += __shfl_xor(dot, off);

        float dx = cx - __shfl(pjx, k);
        float dy = cy - __shfl(pjy, k);
        float dz = cz - __shfl(pjz, k);
        float radial = dx * dx + dy * dy + dz * dz;
        float s = dot + 1.0f / (radial + 1e-8f);   // DIST_W = 1.0, EPS = 1e-8

        float nm = fmaxf(run_m, s);
        float sc = __expf(run_m - nm);             // first iter: exp(-inf)=0
        float w  = __expf(s - nm);
        run_l = run_l * sc + w;
        accv  = accv * sc + w * gv;
        acct  = acct * sc + w * gt;
        ax = ax * sc + w * dx;
        ay = ay * sc + w * dy;
        az = az * sc + w * dz;
        run_m = nm;
    }

    float inv = 1.0f / run_l;
    short* ao = aggb + (size_t)wid * DHID;
    bf16x4 o;
#pragma unroll
    for (int i = 0; i < 4; ++i) o[i] = f2bf(accv[i] * inv);
    *(bf16x4*)(ao + 4 * lane) = o;                // 8B store
    ao[256 + lane] = f2bf(acct * inv);

    if (lane == 0) {
        float s = inv / (float)KNN;   // mean over K of softmax-weighted diffs
        coord_out[3 * wid + 0] = cx + ax * s;
        coord_out[3 * wid + 1] = cy + ay * s;
        coord_out[3 * wid + 2] = cz + az * s;
    }
}

// ---------------------------------------------------------------------------
// Kernel 0: convert weights to bf16 in MFMA-fragment-blocked layout.
// B fragment of lane (lrow=lane&15, kg=lane>>4) for col-tile `tile`,
// k-step t is 8 contiguous k at
//   dst[tile*NT*512 + t*512 + kg*128 + lrow*8 + j]
// so one wave B-load = contiguous 1 KiB.
// ---------------------------------------------------------------------------
__global__ __launch_bounds__(256)
void wconv_kernel(const float* __restrict__ W1, const float* __restrict__ W2,
                  short* __restrict__ Wt1, short* __restrict__ Wt2)
{
    int i = blockIdx.x * 256 + threadIdx.x;
    if (i < 640 * 320) {
        int k = i / 320, c = i - k * 320;               // W1[k][c]
        int tile = c >> 4, lr = c & 15;
        int t = k >> 5, kg = (k >> 3) & 3, j = k & 7;
        Wt1[(size_t)tile * (20 * 512) + t * 512 + kg * 128 + lr * 8 + j] = f2bf(W1[i]);
    } else {
        int q = i - 640 * 320;
        int k = q / 320, c = q - k * 320;               // W2[k][c]
        int tile = c >> 4, lr = c & 15;
        int t = k >> 5, kg = (k >> 3) & 3, j = k & 7;
        Wt2[(size_t)tile * (10 * 512) + t * 512 + kg * 128 + lr * 8 + j] = f2bf(W2[q]);
    }
}

// ---------------------------------------------------------------------------
// MLP kernel 1: h1 = silu([h | agg] @ W1 + b1)   (bf16 out, in ws)
// grid (N/16, 5), block 256 = 4 waves. Wave wv -> col-tile blockIdx.y*4+wv.
// A staged once per block into XOR-swizzled LDS; B contiguous 1 KiB loads.
// Staging: z-tile = 16 rows x 640 shorts = 1280 chunks of 8 shorts.
// ---------------------------------------------------------------------------
__global__ __launch_bounds__(256)
void mlp1_kernel(const float* __restrict__ h,
                 const short* __restrict__ aggb,
                 const short* __restrict__ Wt1,
                 const float* __restrict__ b1,
                 short*       __restrict__ h1)
{
    __shared__ short zs[16 * 640];      // [16 rows][640 z-cols] bf16, 20 KiB

    const int tid  = threadIdx.x;
    const int lane = tid & 63;
    const int wv   = tid >> 6;          // 0..3
    const int lrow = lane & 15;
    const int kg   = lane >> 4;
    const int r0   = blockIdx.x * 16;
    const int tile = blockIdx.y * 4 + wv;   // 0..19

    // stage z = [h(cvt) | agg]: 1280 chunks of 8 shorts (80 chunks/row)
    for (int c = tid; c < 1280; c += 256) {
        int row = c / 80;
        int zc  = (c - row * 80) * 8;   // z col in shorts, 0..632
        int sw  = (row & 7) << 4;
        bf16x8 v;
        if (zc < DHID) {
            const float* hp = h + (size_t)(r0 + row) * DHID + zc;
            f4 lo = *(const f4*)hp;
            f4 hi = *(const f4*)(hp + 4);
#pragma unroll
            for (int j = 0; j < 4; ++j) { v[j] = f2bf(lo[j]); v[4 + j] = f2bf(hi[j]); }
        } else {
            v = *(const bf16x8*)(aggb + (size_t)(r0 + row) * DHID + (zc - DHID));
        }
        *(bf16x8*)((char*)zs + ((row * 1280 + zc * 2) ^ sw)) = v;
    }
    __syncthreads();

    const int   sw    = (lrow & 7) << 4;
    const char* abase = (const char*)zs + lrow * 1280;
    const short* B    = Wt1 + (size_t)tile * (20 * 512) + kg * 128 + lrow * 8;

    f32x4 acc = {};
#pragma unroll 5
    for (int t = 0; t < 20; ++t) {
        bf16x8 a = *(const bf16x8*)(abase + ((t * 64 + kg * 16) ^ sw));
        bf16x8 b = *(const bf16x8*)(B + t * 512);
        acc = __builtin_amdgcn_mfma_f32_16x16x32_bf16(a, b, acc, 0, 0, 0);
    }

    int   colc = tile * 16 + lrow;
    float bb   = b1[colc];
#pragma unroll
    for (int r = 0; r < 4; ++r) {
        int grow = r0 + kg * 4 + r;
        float x = acc[r] + bb;
        x = x / (1.f + __expf(-x));
        h1[(size_t)grow * DHID + colc] = f2bf(x);
    }
}

// ---------------------------------------------------------------------------
// MLP kernel 2: hout = h1 @ W2 + b2 + h
// Same structure as mlp1 (K = 320, 10 steps). Tile = 16 rows x 320 shorts
// = 640 chunks of 8 shorts (40 chunks/row) -> the c<640 loop is correct here.
// ---------------------------------------------------------------------------
__global__ __launch_bounds__(256)
void mlp2_kernel(const float* __restrict__ h,
                 const short* __restrict__ h1,
                 const short* __restrict__ Wt2,
                 const float* __restrict__ b2,
                 float*       __restrict__ hout)
{
    __shared__ short hs[16 * 320];      // 10 KiB, swizzled

    const int tid  = threadIdx.x;
    const int lane = tid & 63;
    const int wv   = tid >> 6;
    const int lrow = lane & 15;
    const int kg   = lane >> 4;
    const int r0   = blockIdx.x * 16;
    const int tile = blockIdx.y * 4 + wv;

    for (int c = tid; c < 640; c += 256) {
        int row = c / 40;
        int zc  = (c - row * 40) * 8;   // 0..312
        int sw  = (row & 7) << 4;
        bf16x8 v = *(const bf16x8*)(h1 + (size_t)(r0 + row) * DHID + zc);
        *(bf16x8*)((char*)hs + ((row * 640 + zc * 2) ^ sw)) = v;
    }
    __syncthreads();

    const int   sw    = (lrow & 7) << 4;
    const char* abase = (const char*)hs + lrow * 640;
    const short* B    = Wt2 + (size_t)tile * (10 * 512) + kg * 128 + lrow * 8;

    f32x4 acc = {};
#pragma unroll 5
    for (int t = 0; t < 10; ++t) {
        bf16x8 a = *(const bf16x8*)(abase + ((t * 64 + kg * 16) ^ sw));
        bf16x8 b = *(const bf16x8*)(B + t * 512);
        acc = __builtin_amdgcn_mfma_f32_16x16x32_bf16(a, b, acc, 0, 0, 0);
    }

    int   colc = tile * 16 + lrow;
    float bb   = b2[colc];
#pragma unroll
    for (int r = 0; r < 4; ++r) {
        int grow = r0 + kg * 4 + r;
        hout[(size_t)grow * DHID + colc] =
            acc[r] + bb + h[(size_t)grow * DHID + colc];
    }
}

// ---------------------------------------------------------------------------
// Fallback: fused MLP, 320 threads = 5 waves x 4 tiles (only if ws is small).
// ---------------------------------------------------------------------------
__global__ __launch_bounds__(320)
void mlp_fused_kernel(const float* __restrict__ h,
                      const short* __restrict__ aggb,
                      const short* __restrict__ Wt1,
                      const short* __restrict__ Wt2,
                      const float* __restrict__ b1,
                      const float* __restrict__ b2,
                      float*       __restrict__ hout)
{
    __shared__ short zs[16 * 640];      // 20 KiB
    __shared__ short h1s[16 * 320];     // 10 KiB

    const int tid  = threadIdx.x;
    const int lane = tid & 63;
    const int wv   = tid >> 6;          // 0..4
    const int lrow = lane & 15;
    const int kg   = lane >> 4;
    const int r0   = blockIdx.x * 16;

    for (int c = tid; c < 1280; c += 320) {
        int row = c / 80;
        int zc  = (c - row * 80) * 8;   // 0..632
        int sw  = (row & 7) << 4;
        bf16x8 v;
        if (zc < DHID) {
            const float* hp = h + (size_t)(r0 + row) * DHID + zc;
            f4 lo = *(const f4*)hp;
            f4 hi = *(const f4*)(hp + 4);
#pragma unroll
            for (int j = 0; j < 4; ++j) { v[j] = f2bf(lo[j]); v[4 + j] = f2bf(hi[j]); }
        } else {
            v = *(const bf16x8*)(aggb + (size_t)(r0 + row) * DHID + (zc - DHID));
        }
        *(bf16x8*)((char*)zs + ((row * 1280 + zc * 2) ^ sw)) = v;
    }
    __syncthreads();

    const int   sw    = (lrow & 7) << 4;
    const char* abase = (const char*)zs + lrow * 1280;

    f32x4 acc[4] = {};
    {
        const short* B = Wt1 + (size_t)(wv * 4) * (20 * 512) + kg * 128 + lrow * 8;
        for (int t = 0; t < 20; ++t) {
            bf16x8 a = *(const bf16x8*)(abase + ((t * 64 + kg * 16) ^ sw));
#pragma unroll
            for (int i = 0; i < 4; ++i) {
                bf16x8 b = *(const bf16x8*)(B + (size_t)i * (20 * 512) + t * 512);
                acc[i] = __builtin_amdgcn_mfma_f32_16x16x32_bf16(a, b, acc[i], 0, 0, 0);
            }
        }
    }
#pragma unroll
    for (int i = 0; i < 4; ++i) {
        int colc = (wv * 4 + i) * 16 + lrow;
        float bb = b1[colc];
#pragma unroll
        for (int r = 0; r < 4; ++r) {
            int row = kg * 4 + r;
            float x = acc[i][r] + bb;
            x = x / (1.f + __expf(-x));
            *(short*)((char*)h1s + ((row * 640 + colc * 2) ^ ((row & 7) << 4))) = f2bf(x);
        }
    }
    __syncthreads();

    f32x4 acc2[4] = {};
    {
        const short* B = Wt2 + (size_t)(wv * 4) * (10 * 512) + kg * 128 + lrow * 8;
        const char* a2base = (const char*)h1s + lrow * 640;
        for (int t = 0; t < 10; ++t) {
            bf16x8 a = *(const bf16x8*)(a2base + ((t * 64 + kg * 16) ^ sw));
#pragma unroll
            for (int i = 0; i < 4; ++i) {
                bf16x8 b = *(const bf16x8*)(B + (size_t)i * (10 * 512) + t * 512);
                acc2[i] = __builtin_amdgcn_mfma_f32_16x16x32_bf16(a, b, acc2[i], 0, 0, 0);
            }
        }
    }
#pragma unroll
    for (int i = 0; i < 4; ++i) {
        int colc = (wv * 4 + i) * 16 + lrow;
        float bb = b2[colc];
#pragma unroll
        for (int r = 0; r < 4; ++r) {
            int grow = r0 + kg * 4 + r;
            hout[(size_t)grow * DHID + colc] =
                acc2[i][r] + bb + h[(size_t)grow * DHID + colc];
        }
    }
}

// ---------------------------------------------------------------------------
extern "C" void kernel_launch(void* const* d_in, const int* in_sizes, int n_in,
                              void* d_out, int out_size, void* d_ws, size_t ws_size,
                              hipStream_t stream)
{
    const float* h     = (const float*)d_in[0];
    const float* coord = (const float*)d_in[1];
    const float* W1    = (const float*)d_in[2];
    const float* b1    = (const float*)d_in[3];
    const float* W2    = (const float*)d_in[4];
    const float* b2    = (const float*)d_in[5];
    const int*   ei    = (const int*)d_in[6];   // [2, N*K] int32

    const int N  = in_sizes[0] / DHID;          // 8192
    const int NK = N * KNN;

    float* out       = (float*)d_out;
    float* hout      = out;                     // [N, 320]
    float* coord_out = out + (size_t)N * DHID;  // [N, 3]

    // ws layout (shorts): aggb[N*320] | Wt1[204800] | Wt2[102400] | h1[N*320]
    short* aggb = (short*)d_ws;
    short* Wt1  = aggb + (size_t)N * DHID;
    short* Wt2  = Wt1 + 20 * 20 * 512;
    short* h1   = Wt2 + 20 * 10 * 512;

    // exact byte requirement of the split path: 11,100,160 B for N=8192
    const size_t need_split =
        ((size_t)N * DHID * 2 /* aggb + h1 */ + 20 * 20 * 512 + 20 * 10 * 512)
        * sizeof(short);

    const int* col = ei + NK;                   // second row of edge_index

    wconv_kernel<<<(640 * 320 + 320 * 320) / 256, 256, 0, stream>>>(W1, W2, Wt1, Wt2);
    edge_kernel<<<N / 4, 256, 0, stream>>>(h, coord, col, aggb, coord_out, N);

    if (ws_size >= need_split) {
        dim3 g(N / 16, 5);
        mlp1_kernel<<<g, 256, 0, stream>>>(h, aggb, Wt1, b1, h1);
        mlp2_kernel<<<g, 256, 0, stream>>>(h, h1, Wt2, b2, hout);
    } else {
        mlp_fused_kernel<<<N / 16, 320, 0, stream>>>(h, aggb, Wt1, Wt2, b1, b2, hout);
    }
}

// Round 11
// 135.290 us; speedup vs baseline: 1.5003x; 1.0280x over previous
//
#include <hip/hip_runtime.h>
#include <hip/hip_bf16.h>
#include <math.h>

// Problem constants (from reference setup)
#define DHID 320     // hidden dim D
#define KNN  30      // neighbors per node

typedef float f4    __attribute__((ext_vector_type(4)));
typedef float f32x4 __attribute__((ext_vector_type(4)));
typedef short bf16x8 __attribute__((ext_vector_type(8)));
typedef short bf16x4 __attribute__((ext_vector_type(4)));

// fp32 -> bf16 bits, round-to-nearest-even
static __device__ __forceinline__ short f2bf(float x) {
    union { float f; unsigned u; } v; v.f = x;
    unsigned r = v.u + 0x7FFFu + ((v.u >> 16) & 1u);
    return (short)(r >> 16);
}

// ---------------------------------------------------------------------------
// Kernel A: per-node attention + aggregation + coord update (one wave/node).
// Online softmax over the K=30 contiguous edges of each node.
// Lane l owns dims {4l..4l+3} (float4) and {256+l} (tail) of the 320-dim row.
// (unchanged from round 10: 42.4 us, FETCH 101 MB — bf16-gather is the next
//  candidate, kept out of this round for single-variable attribution)
// ---------------------------------------------------------------------------
__global__ __launch_bounds__(256)
void edge_kernel(const float* __restrict__ h,
                 const float* __restrict__ coord,
                 const int*   __restrict__ col,       // edge_index row 1
                 short*       __restrict__ aggb,      // [N, D] bf16 out
                 float*       __restrict__ coord_out, // [N, 3] out
                 int N)
{
    int wid  = (int)((blockIdx.x * 256u + threadIdx.x) >> 6);
    int lane = threadIdx.x & 63;
    if (wid >= N) return;

    const float* hi = h + (size_t)wid * DHID;
    f4    hv = *(const f4*)(hi + 4 * lane);
    float ht = hi[256 + lane];

    float cx = coord[3 * wid + 0];
    float cy = coord[3 * wid + 1];
    float cz = coord[3 * wid + 2];

    // load the 30 neighbor indices + their coords once (lanes 0..29)
    const int* cp = col + (size_t)wid * KNN;
    int jv = (lane < KNN) ? cp[lane] : 0;
    float pjx = 0.f, pjy = 0.f, pjz = 0.f;
    if (lane < KNN) {
        pjx = coord[3 * jv + 0];
        pjy = coord[3 * jv + 1];
        pjz = coord[3 * jv + 2];
    }

    float run_m = -INFINITY, run_l = 0.f;
    f4    accv = {0.f, 0.f, 0.f, 0.f};
    float acct = 0.f;
    float ax = 0.f, ay = 0.f, az = 0.f;

#pragma unroll 2
    for (int k = 0; k < KNN; ++k) {
        int j = __shfl(jv, k);
        const float* hj = h + (size_t)j * DHID;
        f4    gv = *(const f4*)(hj + 4 * lane);
        float gt = hj[256 + lane];

        float dot = hv[0] * gv[0];
        dot = fmaf(hv[1], gv[1], dot);
        dot = fmaf(hv[2], gv[2], dot);
        dot = fmaf(hv[3], gv[3], dot);
        dot = fmaf(ht, gt, dot);
        // butterfly: all 64 lanes end with the full 320-dot
#pragma unroll
        for (int off = 32; off; off >>= 1) dot += __shfl_xor(dot, off);

        float dx = cx - __shfl(pjx, k);
        float dy = cy - __shfl(pjy, k);
        float dz = cz - __shfl(pjz, k);
        float radial = dx * dx + dy * dy + dz * dz;
        float s = dot + 1.0f / (radial + 1e-8f);   // DIST_W = 1.0, EPS = 1e-8

        float nm = fmaxf(run_m, s);
        float sc = __expf(run_m - nm);             // first iter: exp(-inf)=0
        float w  = __expf(s - nm);
        run_l = run_l * sc + w;
        accv  = accv * sc + w * gv;
        acct  = acct * sc + w * gt;
        ax = ax * sc + w * dx;
        ay = ay * sc + w * dy;
        az = az * sc + w * dz;
        run_m = nm;
    }

    float inv = 1.0f / run_l;
    short* ao = aggb + (size_t)wid * DHID;
    bf16x4 o;
#pragma unroll
    for (int i = 0; i < 4; ++i) o[i] = f2bf(accv[i] * inv);
    *(bf16x4*)(ao + 4 * lane) = o;                // 8B store
    ao[256 + lane] = f2bf(acct * inv);

    if (lane == 0) {
        float s = inv / (float)KNN;   // mean over K of softmax-weighted diffs
        coord_out[3 * wid + 0] = cx + ax * s;
        coord_out[3 * wid + 1] = cy + ay * s;
        coord_out[3 * wid + 2] = cz + az * s;
    }
}

// ---------------------------------------------------------------------------
// Kernel 0: convert weights to bf16 in MFMA-fragment-blocked layout.
// B fragment of lane (lrow=lane&15, kg=lane>>4) for col-tile `tile`,
// k-step t is 8 contiguous k at
//   dst[tile*NT*512 + t*512 + kg*128 + lrow*8 + j]
// so one wave B-load = contiguous 1 KiB.
// ---------------------------------------------------------------------------
__global__ __launch_bounds__(256)
void wconv_kernel(const float* __restrict__ W1, const float* __restrict__ W2,
                  short* __restrict__ Wt1, short* __restrict__ Wt2)
{
    int i = blockIdx.x * 256 + threadIdx.x;
    if (i < 640 * 320) {
        int k = i / 320, c = i - k * 320;               // W1[k][c]
        int tile = c >> 4, lr = c & 15;
        int t = k >> 5, kg = (k >> 3) & 3, j = k & 7;
        Wt1[(size_t)tile * (20 * 512) + t * 512 + kg * 128 + lr * 8 + j] = f2bf(W1[i]);
    } else {
        int q = i - 640 * 320;
        int k = q / 320, c = q - k * 320;               // W2[k][c]
        int tile = c >> 4, lr = c & 15;
        int t = k >> 5, kg = (k >> 3) & 3, j = k & 7;
        Wt2[(size_t)tile * (10 * 512) + t * 512 + kg * 128 + lr * 8 + j] = f2bf(W2[q]);
    }
}

// ---------------------------------------------------------------------------
// Fused MLP: hout = silu([h|agg]@W1+b1)@W2 + b2 + h
// 256 threads = 4 waves, 16 rows/block, grid N/16 = 512.
// Wave wv owns col-tiles {5wv..5wv+4} in BOTH GEMMs -> 5 independent MFMA
// accumulator chains per wave (ILP), staging amortized over 100 MFMAs/wave,
// h1 passes through swizzled LDS (no global round-trip, no 2nd kernel).
// A: XOR-swizzled LDS (round-10-validated addressing).
// B: fragment-blocked contiguous 1 KiB wave-loads (round-10-validated).
// ---------------------------------------------------------------------------
__global__ __launch_bounds__(256)
void mlp_fused_kernel(const float* __restrict__ h,
                      const short* __restrict__ aggb,
                      const short* __restrict__ Wt1,
                      const short* __restrict__ Wt2,
                      const float* __restrict__ b1,
                      const float* __restrict__ b2,
                      float*       __restrict__ hout)
{
    __shared__ short zs[16 * 640];      // [16][640] bf16, swizzled, 20 KiB
    __shared__ short h1s[16 * 320];     // [16][320] bf16, swizzled, 10 KiB

    const int tid  = threadIdx.x;
    const int lane = tid & 63;
    const int wv   = tid >> 6;          // 0..3
    const int lrow = lane & 15;
    const int kg   = lane >> 4;
    const int r0   = blockIdx.x * 16;

    // stage z = [h(cvt bf16) | agg]: 1280 chunks of 8 shorts (80/row)
    for (int c = tid; c < 1280; c += 256) {
        int row = c / 80;
        int zc  = (c - row * 80) * 8;   // 0..632
        int sw  = (row & 7) << 4;
        bf16x8 v;
        if (zc < DHID) {
            const float* hp = h + (size_t)(r0 + row) * DHID + zc;
            f4 lo = *(const f4*)hp;
            f4 hi = *(const f4*)(hp + 4);
#pragma unroll
            for (int j = 0; j < 4; ++j) { v[j] = f2bf(lo[j]); v[4 + j] = f2bf(hi[j]); }
        } else {
            v = *(const bf16x8*)(aggb + (size_t)(r0 + row) * DHID + (zc - DHID));
        }
        *(bf16x8*)((char*)zs + ((row * 1280 + zc * 2) ^ sw)) = v;
    }
    __syncthreads();

    const int   sw    = (lrow & 7) << 4;
    const char* abase = (const char*)zs + lrow * 1280;

    // ---- GEMM1: [16 x 640] @ W1, 5 tiles/wave, 20 K-steps ----
    f32x4 acc[5] = {};
    {
        const short* B = Wt1 + (size_t)(wv * 5) * (20 * 512) + kg * 128 + lrow * 8;
        for (int t = 0; t < 20; ++t) {
            bf16x8 a = *(const bf16x8*)(abase + ((t * 64 + kg * 16) ^ sw));
#pragma unroll
            for (int i = 0; i < 5; ++i) {
                bf16x8 b = *(const bf16x8*)(B + (size_t)i * (20 * 512) + t * 512);
                acc[i] = __builtin_amdgcn_mfma_f32_16x16x32_bf16(a, b, acc[i], 0, 0, 0);
            }
        }
    }

    // epilogue 1: bias + SiLU -> swizzled h1s
#pragma unroll
    for (int i = 0; i < 5; ++i) {
        int colc = (wv * 5 + i) * 16 + lrow;
        float bb = b1[colc];
#pragma unroll
        for (int r = 0; r < 4; ++r) {
            int row = kg * 4 + r;
            float x = acc[i][r] + bb;
            x = x / (1.f + __expf(-x));
            *(short*)((char*)h1s + ((row * 640 + colc * 2) ^ ((row & 7) << 4))) = f2bf(x);
        }
    }
    __syncthreads();

    // ---- GEMM2: [16 x 320] @ W2, 5 tiles/wave, 10 K-steps ----
    f32x4 acc2[5] = {};
    {
        const short* B = Wt2 + (size_t)(wv * 5) * (10 * 512) + kg * 128 + lrow * 8;
        const char* a2base = (const char*)h1s + lrow * 640;
        for (int t = 0; t < 10; ++t) {
            bf16x8 a = *(const bf16x8*)(a2base + ((t * 64 + kg * 16) ^ sw));
#pragma unroll
            for (int i = 0; i < 5; ++i) {
                bf16x8 b = *(const bf16x8*)(B + (size_t)i * (10 * 512) + t * 512);
                acc2[i] = __builtin_amdgcn_mfma_f32_16x16x32_bf16(a, b, acc2[i], 0, 0, 0);
            }
        }
    }

    // epilogue 2: bias + residual (fp32 h re-read) -> hout
#pragma unroll
    for (int i = 0; i < 5; ++i) {
        int colc = (wv * 5 + i) * 16 + lrow;
        float bb = b2[colc];
#pragma unroll
        for (int r = 0; r < 4; ++r) {
            int grow = r0 + kg * 4 + r;
            hout[(size_t)grow * DHID + colc] =
                acc2[i][r] + bb + h[(size_t)grow * DHID + colc];
        }
    }
}

// ---------------------------------------------------------------------------
extern "C" void kernel_launch(void* const* d_in, const int* in_sizes, int n_in,
                              void* d_out, int out_size, void* d_ws, size_t ws_size,
                              hipStream_t stream)
{
    const float* h     = (const float*)d_in[0];
    const float* coord = (const float*)d_in[1];
    const float* W1    = (const float*)d_in[2];
    const float* b1    = (const float*)d_in[3];
    const float* W2    = (const float*)d_in[4];
    const float* b2    = (const float*)d_in[5];
    const int*   ei    = (const int*)d_in[6];   // [2, N*K] int32

    const int N  = in_sizes[0] / DHID;          // 8192
    const int NK = N * KNN;

    float* out       = (float*)d_out;
    float* hout      = out;                     // [N, 320]
    float* coord_out = out + (size_t)N * DHID;  // [N, 3]

    // ws layout (shorts): aggb[N*320] | Wt1[204800] | Wt2[102400]
    // = 5.95 MB total; d_ws is ~268 MB (observed via harness poison fills).
    short* aggb = (short*)d_ws;
    short* Wt1  = aggb + (size_t)N * DHID;
    short* Wt2  = Wt1 + 20 * 20 * 512;

    const int* col = ei + NK;                   // second row of edge_index

    edge_kernel<<<N / 4, 256, 0, stream>>>(h, coord, col, aggb, coord_out, N);
    wconv_kernel<<<(640 * 320 + 320 * 320) / 256, 256, 0, stream>>>(W1, W2, Wt1, Wt2);
    mlp_fused_kernel<<<N / 16, 256, 0, stream>>>(h, aggb, Wt1, Wt2, b1, b2, hout);
}